// Round 1
// baseline (379.370 us; speedup 1.0000x reference)
//
#include <hip/hip_runtime.h>

// RGCNBlock: y = rgcn2(gelu(bn2(rgcn1(gelu(bn1(x)))))) + x
// N=50000 nodes, K=16 neighbors, F=128 features, f32 in/out.
// Matmuls in bf16 MFMA (16x16x32), stats/accum in f32. b1 cancels in BN2.

#define NN 50000
#define FF 128

typedef __bf16 v8bf __attribute__((ext_vector_type(8)));
typedef float  v4f  __attribute__((ext_vector_type(4)));

__device__ __forceinline__ unsigned short f2bf(float f) {
  unsigned int u = __builtin_bit_cast(unsigned int, f);
  u += 0x7FFFu + ((u >> 16) & 1u);          // RNE
  return (unsigned short)(u >> 16);
}
__device__ __forceinline__ float bf2f(unsigned short s) {
  unsigned int u = ((unsigned int)s) << 16;
  return __builtin_bit_cast(float, u);
}
__device__ __forceinline__ float gelu_f(float y) {
  return 0.5f * y * (1.0f + erff(y * 0.70710678118654752f));
}

// ---------------- W (F x K*F f32) -> bf16 in MFMA-B-fragment order ----------
// frag id = k4*8 + c  (k4 = 32-wide K-window 0..63, c = 16-wide col tile 0..7)
// within frag: lane L holds W[c*16+(L&15), k4*32+(L>>4)*8 + j], j=0..7 (16B)
__global__ void wconv_kernel(const float* __restrict__ W1, const float* __restrict__ W2,
                             unsigned short* __restrict__ Wt1, unsigned short* __restrict__ Wt2) {
  int t = blockIdx.x * 256 + threadIdx.x;            // 65536 total
  const float* W = (t >= 32768) ? W2 : W1;
  unsigned short* Wt = (t >= 32768) ? Wt2 : Wt1;
  int r = t & 32767;
  int frag = r >> 6, lane = r & 63;
  int k4 = frag >> 3, c = frag & 7;
  int o  = c * 16 + (lane & 15);
  int kd = k4 * 32 + (lane >> 4) * 8;
  const float* src = W + o * 2048 + kd;
  unsigned short* dst = Wt + r * 8;
#pragma unroll
  for (int j = 0; j < 8; ++j) dst[j] = f2bf(src[j]);
}

// ---------------- BN stats over x (f32), deterministic two-phase ------------
__global__ void bn_stats_kernel(const float* __restrict__ x, float* __restrict__ part) {
  float s0=0,s1=0,s2=0,s3=0,q0=0,q1=0,q2=0,q3=0;
  for (int cb = blockIdx.x; cb < (NN*FF/1024); cb += 256) {
    float4 v = reinterpret_cast<const float4*>(x)[cb * 256 + threadIdx.x];
    s0+=v.x; q0+=v.x*v.x; s1+=v.y; q1+=v.y*v.y;
    s2+=v.z; q2+=v.z*v.z; s3+=v.w; q3+=v.w*v.w;
  }
  __shared__ float ls[1024], lsq[1024];
  int fb = (threadIdx.x & 31) * 4;
  int sl = threadIdx.x >> 5;
  ls[sl*128+fb]   = s0; ls[sl*128+fb+1]  = s1; ls[sl*128+fb+2]  = s2; ls[sl*128+fb+3]  = s3;
  lsq[sl*128+fb]  = q0; lsq[sl*128+fb+1] = q1; lsq[sl*128+fb+2] = q2; lsq[sl*128+fb+3] = q3;
  __syncthreads();
  if (threadIdx.x < 128) {
    float S=0,Q=0;
#pragma unroll
    for (int s2i=0; s2i<8; ++s2i){ S += ls[s2i*128+threadIdx.x]; Q += lsq[s2i*128+threadIdx.x]; }
    part[blockIdx.x*256 + threadIdx.x]       = S;
    part[blockIdx.x*256 + 128 + threadIdx.x] = Q;
  }
}

__global__ void bn_reduce_kernel(const float* __restrict__ part, int nb,
                                 const float* __restrict__ gamma, const float* __restrict__ beta,
                                 float* __restrict__ scsh) {
  int f = threadIdx.x;                                 // 128 threads
  float S = 0.f, Q = 0.f;
  for (int b = 0; b < nb; ++b) { S += part[b*256+f]; Q += part[b*256+128+f]; }
  float inv  = 1.0f / (float)NN;
  float mean = S * inv;
  float var  = fmaxf(Q * inv - mean * mean, 0.0f);
  float sc   = gamma[f] * rsqrtf(var + 1e-5f);
  scsh[f]       = sc;
  scsh[128 + f] = beta[f] - mean * sc;
}

// ---------------- apply BN + GELU, f32 source -> bf16 ----------------------
__global__ void apply1_kernel(const float* __restrict__ x, const float* __restrict__ scsh,
                              unsigned short* __restrict__ h1) {
  int stride = gridDim.x * blockDim.x;
  for (int c = blockIdx.x * blockDim.x + threadIdx.x; c < NN*FF/4; c += stride) {
    float4 v = reinterpret_cast<const float4*>(x)[c];
    int f = (c * 4) & 127;
    ushort4 o;
    o.x = f2bf(gelu_f(v.x * scsh[f]   + scsh[128+f]));
    o.y = f2bf(gelu_f(v.y * scsh[f+1] + scsh[128+f+1]));
    o.z = f2bf(gelu_f(v.z * scsh[f+2] + scsh[128+f+2]));
    o.w = f2bf(gelu_f(v.w * scsh[f+3] + scsh[128+f+3]));
    reinterpret_cast<ushort4*>(h1)[c] = o;
  }
}

// ---------------- apply BN + GELU, bf16 source -> bf16 ---------------------
__global__ void apply2_kernel(const unsigned short* __restrict__ t1, const float* __restrict__ scsh,
                              unsigned short* __restrict__ h2) {
  int stride = gridDim.x * blockDim.x;
  for (int c = blockIdx.x * blockDim.x + threadIdx.x; c < NN*FF/4; c += stride) {
    ushort4 v = reinterpret_cast<const ushort4*>(t1)[c];
    int f = (c * 4) & 127;
    ushort4 o;
    o.x = f2bf(gelu_f(bf2f(v.x) * scsh[f]   + scsh[128+f]));
    o.y = f2bf(gelu_f(bf2f(v.y) * scsh[f+1] + scsh[128+f+1]));
    o.z = f2bf(gelu_f(bf2f(v.z) * scsh[f+2] + scsh[128+f+2]));
    o.w = f2bf(gelu_f(bf2f(v.w) * scsh[f+3] + scsh[128+f+3]));
    reinterpret_cast<ushort4*>(h2)[c] = o;
  }
}

// ---------------- RGCN: out[n,o] = sum_{k,f} h[nbr[n,k],f] * W[o,k*128+f] --
// Block = 4 waves, 128 nodes. Wave = 32 nodes x 128 out-feats.
// A frags gathered direct global->VGPR; B frags coalesced from swizzled Wt.
template<bool STATS>
__global__ __launch_bounds__(256) void rgcn_kernel(
    const unsigned short* __restrict__ h,
    const unsigned short* __restrict__ Wt,
    const int* __restrict__ graph,
    const float* __restrict__ bias,
    const float* __restrict__ xres,
    float* __restrict__ outf,
    unsigned short* __restrict__ outb,
    float* __restrict__ part)
{
  const int tid  = threadIdx.x;
  const int wv   = tid >> 6;
  const int lane = tid & 63;
  const int l15  = lane & 15;
  const int lq   = lane >> 4;
  const int nodebase = blockIdx.x * 128 + wv * 32;

  v4f acc[2][8];
#pragma unroll
  for (int rf = 0; rf < 2; ++rf)
#pragma unroll
    for (int c = 0; c < 8; ++c) acc[rf][c] = (v4f){0.f, 0.f, 0.f, 0.f};

  const int an0 = min(nodebase + l15, NN - 1);       // A-row node (rf=0)
  const int an1 = min(nodebase + 16 + l15, NN - 1);  // A-row node (rf=1)

  int ni0 = graph[(an0 * 16 + 0) * 2 + 1];
  int ni1 = graph[(an1 * 16 + 0) * 2 + 1];

#pragma unroll 1
  for (int k = 0; k < 16; ++k) {
    int i0 = min(max(ni0, 0), NN - 1);
    int i1 = min(max(ni1, 0), NN - 1);
    if (k < 15) {                                    // prefetch next slot's indices
      ni0 = graph[(an0 * 16 + k + 1) * 2 + 1];
      ni1 = graph[(an1 * 16 + k + 1) * 2 + 1];
    }
    const unsigned short* r0 = h + i0 * 128 + lq * 8;
    const unsigned short* r1 = h + i1 * 128 + lq * 8;
    v8bf a0[4], a1[4];
#pragma unroll
    for (int w4 = 0; w4 < 4; ++w4) {                 // issue all 8 gathers up front
      a0[w4] = *reinterpret_cast<const v8bf*>(r0 + w4 * 32);
      a1[w4] = *reinterpret_cast<const v8bf*>(r1 + w4 * 32);
    }
    const unsigned short* wp = Wt + (k * 4) * 4096 + lane * 8;
#pragma unroll
    for (int w4 = 0; w4 < 4; ++w4) {
#pragma unroll
      for (int c = 0; c < 8; ++c) {
        v8bf b = *reinterpret_cast<const v8bf*>(wp + w4 * 4096 + c * 512);
        acc[0][c] = __builtin_amdgcn_mfma_f32_16x16x32_bf16(a0[w4], b, acc[0][c], 0, 0, 0);
        acc[1][c] = __builtin_amdgcn_mfma_f32_16x16x32_bf16(a1[w4], b, acc[1][c], 0, 0, 0);
      }
    }
  }

  if constexpr (STATS) {
    __shared__ float lds_s[4][128];
    __shared__ float lds_q[4][128];
#pragma unroll
    for (int c = 0; c < 8; ++c) {
      float s = 0.f, q = 0.f;
#pragma unroll
      for (int rf = 0; rf < 2; ++rf) {
#pragma unroll
        for (int j = 0; j < 4; ++j) {
          int node = nodebase + rf * 16 + lq * 4 + j;   // C/D: row=(lane>>4)*4+reg
          float v  = acc[rf][c][j];
          if (node < NN) {
            s += v; q += v * v;
            outb[node * 128 + c * 16 + l15] = f2bf(v);  // col = lane&15
          }
        }
      }
      s += __shfl_xor(s, 16, 64); s += __shfl_xor(s, 32, 64);
      q += __shfl_xor(q, 16, 64); q += __shfl_xor(q, 32, 64);
      if (lq == 0) { lds_s[wv][c * 16 + l15] = s; lds_q[wv][c * 16 + l15] = q; }
    }
    __syncthreads();
    if (tid < 128) {
      float S = lds_s[0][tid] + lds_s[1][tid] + lds_s[2][tid] + lds_s[3][tid];
      float Q = lds_q[0][tid] + lds_q[1][tid] + lds_q[2][tid] + lds_q[3][tid];
      part[blockIdx.x * 256 + tid]       = S;
      part[blockIdx.x * 256 + 128 + tid] = Q;
    }
  } else {
#pragma unroll
    for (int c = 0; c < 8; ++c) {
      float bv = bias[c * 16 + l15];
#pragma unroll
      for (int rf = 0; rf < 2; ++rf) {
#pragma unroll
        for (int j = 0; j < 4; ++j) {
          int node = nodebase + rf * 16 + lq * 4 + j;
          if (node < NN) {
            int idx = node * 128 + c * 16 + l15;
            outf[idx] = acc[rf][c][j] + bv + xres[idx];
          }
        }
      }
    }
  }
}

extern "C" void kernel_launch(void* const* d_in, const int* in_sizes, int n_in,
                              void* d_out, int out_size, void* d_ws, size_t ws_size,
                              hipStream_t stream) {
  const float* x      = (const float*)d_in[0];
  const int*   graph  = (const int*)d_in[1];
  const float* gamma1 = (const float*)d_in[2];
  const float* beta1  = (const float*)d_in[3];
  const float* W1     = (const float*)d_in[4];
  // d_in[5] = b1 : provably cancels inside BN2 (per-feature shift), skipped
  const float* gamma2 = (const float*)d_in[6];
  const float* beta2  = (const float*)d_in[7];
  const float* W2     = (const float*)d_in[8];
  const float* b2     = (const float*)d_in[9];
  float* out = (float*)d_out;

  char* ws = (char*)d_ws;
  // ws layout (bytes): h1/h2 bf16 12.8M | t1 bf16 12.8M | Wt1 512K | Wt2 512K
  //                    | p1 256K | p2 400K | scsh1 1K | scsh2 1K   (~27.3MB total)
  unsigned short* h1  = (unsigned short*)(ws);
  unsigned short* t1  = (unsigned short*)(ws + 12800000);
  unsigned short* Wt1 = (unsigned short*)(ws + 25600000);
  unsigned short* Wt2 = (unsigned short*)(ws + 26124288);
  float* p1    = (float*)(ws + 26648576);
  float* p2    = (float*)(ws + 26910720);
  float* scsh1 = (float*)(ws + 27311104);
  float* scsh2 = (float*)(ws + 27312128);

  wconv_kernel<<<256, 256, 0, stream>>>(W1, W2, Wt1, Wt2);
  bn_stats_kernel<<<256, 256, 0, stream>>>(x, p1);
  bn_reduce_kernel<<<1, 128, 0, stream>>>(p1, 256, gamma1, beta1, scsh1);
  apply1_kernel<<<2048, 256, 0, stream>>>(x, scsh1, h1);
  rgcn_kernel<true><<<391, 256, 0, stream>>>(h1, Wt1, graph, nullptr, nullptr, nullptr, t1, p2);
  bn_reduce_kernel<<<1, 128, 0, stream>>>(p2, 391, gamma2, beta2, scsh2);
  apply2_kernel<<<2048, 256, 0, stream>>>(t1, scsh2, h1);   // h2 reuses h1 buffer
  rgcn_kernel<false><<<391, 256, 0, stream>>>(h1, Wt2, graph, b2, x, out, nullptr, nullptr);
}

// Round 2
// 245.934 us; speedup vs baseline: 1.5426x; 1.5426x over previous
//
#include <hip/hip_runtime.h>

// RGCNBlock: y = rgcn2(gelu(bn2(rgcn1(gelu(bn1(x)))))) + x
// N=50000 nodes, K=16 neighbors, F=128 features, f32 in/out.
// Matmuls in bf16 MFMA (16x16x32), stats/accum in f32. b1 cancels in BN2.

#define NN 50000
#define FF 128

typedef __bf16 v8bf __attribute__((ext_vector_type(8)));
typedef float  v4f  __attribute__((ext_vector_type(4)));

__device__ __forceinline__ unsigned short f2bf(float f) {
  unsigned int u = __builtin_bit_cast(unsigned int, f);
  u += 0x7FFFu + ((u >> 16) & 1u);          // RNE
  return (unsigned short)(u >> 16);
}
__device__ __forceinline__ float bf2f(unsigned short s) {
  unsigned int u = ((unsigned int)s) << 16;
  return __builtin_bit_cast(float, u);
}
__device__ __forceinline__ float gelu_f(float y) {
  return 0.5f * y * (1.0f + erff(y * 0.70710678118654752f));
}

// ---------------- W (F x K*F f32) -> bf16 in MFMA-B-fragment order ----------
// frag id = k4*8 + c  (k4 = 32-wide K-window 0..63, c = 16-wide col tile 0..7)
// within frag: lane L holds W[c*16+(L&15), k4*32+(L>>4)*8 + j], j=0..7 (16B)
__global__ void wconv_kernel(const float* __restrict__ W1, const float* __restrict__ W2,
                             unsigned short* __restrict__ Wt1, unsigned short* __restrict__ Wt2) {
  int t = blockIdx.x * 256 + threadIdx.x;            // 65536 total
  const float* W = (t >= 32768) ? W2 : W1;
  unsigned short* Wt = (t >= 32768) ? Wt2 : Wt1;
  int r = t & 32767;
  int frag = r >> 6, lane = r & 63;
  int k4 = frag >> 3, c = frag & 7;
  int o  = c * 16 + (lane & 15);
  int kd = k4 * 32 + (lane >> 4) * 8;
  const float* src = W + o * 2048 + kd;
  unsigned short* dst = Wt + r * 8;
#pragma unroll
  for (int j = 0; j < 8; ++j) dst[j] = f2bf(src[j]);
}

// ---------------- BN stats over x (f32), deterministic two-phase ------------
__global__ void bn_stats_kernel(const float* __restrict__ x, float* __restrict__ part) {
  float s0=0,s1=0,s2=0,s3=0,q0=0,q1=0,q2=0,q3=0;
  for (int cb = blockIdx.x; cb < (NN*FF/1024); cb += 256) {
    float4 v = reinterpret_cast<const float4*>(x)[cb * 256 + threadIdx.x];
    s0+=v.x; q0+=v.x*v.x; s1+=v.y; q1+=v.y*v.y;
    s2+=v.z; q2+=v.z*v.z; s3+=v.w; q3+=v.w*v.w;
  }
  __shared__ float ls[1024], lsq[1024];
  int fb = (threadIdx.x & 31) * 4;
  int sl = threadIdx.x >> 5;
  ls[sl*128+fb]   = s0; ls[sl*128+fb+1]  = s1; ls[sl*128+fb+2]  = s2; ls[sl*128+fb+3]  = s3;
  lsq[sl*128+fb]  = q0; lsq[sl*128+fb+1] = q1; lsq[sl*128+fb+2] = q2; lsq[sl*128+fb+3] = q3;
  __syncthreads();
  if (threadIdx.x < 128) {
    float S=0,Q=0;
#pragma unroll
    for (int s2i=0; s2i<8; ++s2i){ S += ls[s2i*128+threadIdx.x]; Q += lsq[s2i*128+threadIdx.x]; }
    part[blockIdx.x*256 + threadIdx.x]       = S;
    part[blockIdx.x*256 + 128 + threadIdx.x] = Q;
  }
}

// ---------------- final reduce: 1 block x 1024 thr, 8 groups x 128 feats ----
__global__ __launch_bounds__(1024) void bn_reduce_kernel(
    const float* __restrict__ part, int nb,
    const float* __restrict__ gamma, const float* __restrict__ beta,
    float* __restrict__ scsh) {
  int f = threadIdx.x & 127;
  int g = threadIdx.x >> 7;                            // 0..7
  float S = 0.f, Q = 0.f;
  for (int b = g; b < nb; b += 8) {                    // independent loads, deep pipeline
    S += part[b * 256 + f];
    Q += part[b * 256 + 128 + f];
  }
  __shared__ float ls[8][128], lq[8][128];
  ls[g][f] = S; lq[g][f] = Q;
  __syncthreads();
  if (threadIdx.x < 128) {
    float St = 0.f, Qt = 0.f;
#pragma unroll
    for (int i = 0; i < 8; ++i) { St += ls[i][f]; Qt += lq[i][f]; }
    float inv  = 1.0f / (float)NN;
    float mean = St * inv;
    float var  = fmaxf(Qt * inv - mean * mean, 0.0f);
    float sc   = gamma[f] * rsqrtf(var + 1e-5f);
    scsh[f]       = sc;
    scsh[128 + f] = beta[f] - mean * sc;
  }
}

// ---------------- apply BN + GELU, f32 source -> bf16 ----------------------
__global__ void apply1_kernel(const float* __restrict__ x, const float* __restrict__ scsh,
                              unsigned short* __restrict__ h1) {
  int stride = gridDim.x * blockDim.x;
  for (int c = blockIdx.x * blockDim.x + threadIdx.x; c < NN*FF/4; c += stride) {
    float4 v = reinterpret_cast<const float4*>(x)[c];
    int f = (c * 4) & 127;
    ushort4 o;
    o.x = f2bf(gelu_f(v.x * scsh[f]   + scsh[128+f]));
    o.y = f2bf(gelu_f(v.y * scsh[f+1] + scsh[128+f+1]));
    o.z = f2bf(gelu_f(v.z * scsh[f+2] + scsh[128+f+2]));
    o.w = f2bf(gelu_f(v.w * scsh[f+3] + scsh[128+f+3]));
    reinterpret_cast<ushort4*>(h1)[c] = o;
  }
}

// ---------------- apply BN + GELU, bf16 source -> bf16 ---------------------
__global__ void apply2_kernel(const unsigned short* __restrict__ t1, const float* __restrict__ scsh,
                              unsigned short* __restrict__ h2) {
  int stride = gridDim.x * blockDim.x;
  for (int c = blockIdx.x * blockDim.x + threadIdx.x; c < NN*FF/4; c += stride) {
    ushort4 v = reinterpret_cast<const ushort4*>(t1)[c];
    int f = (c * 4) & 127;
    ushort4 o;
    o.x = f2bf(gelu_f(bf2f(v.x) * scsh[f]   + scsh[128+f]));
    o.y = f2bf(gelu_f(bf2f(v.y) * scsh[f+1] + scsh[128+f+1]));
    o.z = f2bf(gelu_f(bf2f(v.z) * scsh[f+2] + scsh[128+f+2]));
    o.w = f2bf(gelu_f(bf2f(v.w) * scsh[f+3] + scsh[128+f+3]));
    reinterpret_cast<ushort4*>(h2)[c] = o;
  }
}

// ---------------- RGCN: out[n,o] = sum_{k,f} h[nbr[n,k],f] * W[o,k*128+f] --
// Block = 4 waves, 128 nodes. Wave = 32 nodes x 128 out-feats.
// A frags gathered direct global->VGPR; B frags coalesced from swizzled Wt.
template<bool STATS>
__global__ __launch_bounds__(256) void rgcn_kernel(
    const unsigned short* __restrict__ h,
    const unsigned short* __restrict__ Wt,
    const int* __restrict__ graph,
    const float* __restrict__ bias,
    const float* __restrict__ xres,
    float* __restrict__ outf,
    unsigned short* __restrict__ outb,
    float* __restrict__ part)
{
  const int tid  = threadIdx.x;
  const int wv   = tid >> 6;
  const int lane = tid & 63;
  const int l15  = lane & 15;
  const int lq   = lane >> 4;
  const int nodebase = blockIdx.x * 128 + wv * 32;

  v4f acc[2][8];
#pragma unroll
  for (int rf = 0; rf < 2; ++rf)
#pragma unroll
    for (int c = 0; c < 8; ++c) acc[rf][c] = (v4f){0.f, 0.f, 0.f, 0.f};

  const int an0 = min(nodebase + l15, NN - 1);       // A-row node (rf=0)
  const int an1 = min(nodebase + 16 + l15, NN - 1);  // A-row node (rf=1)

  int ni0 = graph[(an0 * 16 + 0) * 2 + 1];
  int ni1 = graph[(an1 * 16 + 0) * 2 + 1];

#pragma unroll 1
  for (int k = 0; k < 16; ++k) {
    int i0 = min(max(ni0, 0), NN - 1);
    int i1 = min(max(ni1, 0), NN - 1);
    if (k < 15) {                                    // prefetch next slot's indices
      ni0 = graph[(an0 * 16 + k + 1) * 2 + 1];
      ni1 = graph[(an1 * 16 + k + 1) * 2 + 1];
    }
    const unsigned short* r0 = h + i0 * 128 + lq * 8;
    const unsigned short* r1 = h + i1 * 128 + lq * 8;
    v8bf a0[4], a1[4];
#pragma unroll
    for (int w4 = 0; w4 < 4; ++w4) {                 // issue all 8 gathers up front
      a0[w4] = *reinterpret_cast<const v8bf*>(r0 + w4 * 32);
      a1[w4] = *reinterpret_cast<const v8bf*>(r1 + w4 * 32);
    }
    const unsigned short* wp = Wt + (k * 4) * 4096 + lane * 8;
#pragma unroll
    for (int w4 = 0; w4 < 4; ++w4) {
#pragma unroll
      for (int c = 0; c < 8; ++c) {
        v8bf b = *reinterpret_cast<const v8bf*>(wp + w4 * 4096 + c * 512);
        acc[0][c] = __builtin_amdgcn_mfma_f32_16x16x32_bf16(a0[w4], b, acc[0][c], 0, 0, 0);
        acc[1][c] = __builtin_amdgcn_mfma_f32_16x16x32_bf16(a1[w4], b, acc[1][c], 0, 0, 0);
      }
    }
  }

  if constexpr (STATS) {
    __shared__ float lds_s[4][128];
    __shared__ float lds_q[4][128];
#pragma unroll
    for (int c = 0; c < 8; ++c) {
      float s = 0.f, q = 0.f;
#pragma unroll
      for (int rf = 0; rf < 2; ++rf) {
#pragma unroll
        for (int j = 0; j < 4; ++j) {
          int node = nodebase + rf * 16 + lq * 4 + j;   // C/D: row=(lane>>4)*4+reg
          float v  = acc[rf][c][j];
          if (node < NN) {
            s += v; q += v * v;
            outb[node * 128 + c * 16 + l15] = f2bf(v);  // col = lane&15
          }
        }
      }
      s += __shfl_xor(s, 16, 64); s += __shfl_xor(s, 32, 64);
      q += __shfl_xor(q, 16, 64); q += __shfl_xor(q, 32, 64);
      if (lq == 0) { lds_s[wv][c * 16 + l15] = s; lds_q[wv][c * 16 + l15] = q; }
    }
    __syncthreads();
    if (tid < 128) {
      float S = lds_s[0][tid] + lds_s[1][tid] + lds_s[2][tid] + lds_s[3][tid];
      float Q = lds_q[0][tid] + lds_q[1][tid] + lds_q[2][tid] + lds_q[3][tid];
      part[blockIdx.x * 256 + tid]       = S;
      part[blockIdx.x * 256 + 128 + tid] = Q;
    }
  } else {
#pragma unroll
    for (int c = 0; c < 8; ++c) {
      float bv = bias[c * 16 + l15];
#pragma unroll
      for (int rf = 0; rf < 2; ++rf) {
#pragma unroll
        for (int j = 0; j < 4; ++j) {
          int node = nodebase + rf * 16 + lq * 4 + j;
          if (node < NN) {
            int idx = node * 128 + c * 16 + l15;
            outf[idx] = acc[rf][c][j] + bv + xres[idx];
          }
        }
      }
    }
  }
}

extern "C" void kernel_launch(void* const* d_in, const int* in_sizes, int n_in,
                              void* d_out, int out_size, void* d_ws, size_t ws_size,
                              hipStream_t stream) {
  const float* x      = (const float*)d_in[0];
  const int*   graph  = (const int*)d_in[1];
  const float* gamma1 = (const float*)d_in[2];
  const float* beta1  = (const float*)d_in[3];
  const float* W1     = (const float*)d_in[4];
  // d_in[5] = b1 : provably cancels inside BN2 (per-feature shift), skipped
  const float* gamma2 = (const float*)d_in[6];
  const float* beta2  = (const float*)d_in[7];
  const float* W2     = (const float*)d_in[8];
  const float* b2     = (const float*)d_in[9];
  float* out = (float*)d_out;

  char* ws = (char*)d_ws;
  // ws layout (bytes): h1/h2 bf16 12.8M | t1 bf16 12.8M | Wt1 512K | Wt2 512K
  //                    | p1 256K | p2 400K | scsh1 1K | scsh2 1K   (~27.3MB total)
  unsigned short* h1  = (unsigned short*)(ws);
  unsigned short* t1  = (unsigned short*)(ws + 12800000);
  unsigned short* Wt1 = (unsigned short*)(ws + 25600000);
  unsigned short* Wt2 = (unsigned short*)(ws + 26124288);
  float* p1    = (float*)(ws + 26648576);
  float* p2    = (float*)(ws + 26910720);
  float* scsh1 = (float*)(ws + 27311104);
  float* scsh2 = (float*)(ws + 27312128);

  wconv_kernel<<<256, 256, 0, stream>>>(W1, W2, Wt1, Wt2);
  bn_stats_kernel<<<256, 256, 0, stream>>>(x, p1);
  bn_reduce_kernel<<<1, 1024, 0, stream>>>(p1, 256, gamma1, beta1, scsh1);
  apply1_kernel<<<2048, 256, 0, stream>>>(x, scsh1, h1);
  rgcn_kernel<true><<<391, 256, 0, stream>>>(h1, Wt1, graph, nullptr, nullptr, nullptr, t1, p2);
  bn_reduce_kernel<<<1, 1024, 0, stream>>>(p2, 391, gamma2, beta2, scsh2);
  apply2_kernel<<<2048, 256, 0, stream>>>(t1, scsh2, h1);   // h2 reuses h1 buffer
  rgcn_kernel<false><<<391, 256, 0, stream>>>(h1, Wt2, graph, b2, x, out, nullptr, nullptr);
}